// Round 6
// baseline (1386.096 us; speedup 1.0000x reference)
//
#include <hip/hip_runtime.h>
#include <cstddef>
#include <cmath>

// ============================ CSR build ============================
__global__ void k_init_cnt(unsigned int* __restrict__ cnt, int N) {
    int i = blockIdx.x * 256 + threadIdx.x;
    if (i < N) cnt[i] = 1u;   // self-loop pre-counted
}

__global__ void k_count(const int* __restrict__ ei, int E, unsigned int* __restrict__ cnt) {
    int e = blockIdx.x * 256 + threadIdx.x;
    if (e < E) atomicAdd(&cnt[ei[E + e]], 1u);
}

__global__ __launch_bounds__(1024) void k_scan(const unsigned int* __restrict__ cnt,
                                               unsigned int* __restrict__ off, int N) {
    __shared__ unsigned int sums[1024];
    int t = threadIdx.x;
    int chunk = (N + 1023) >> 10;
    int lo = t * chunk, hi = min(lo + chunk, N);
    unsigned int s = 0;
    for (int i = lo; i < hi; ++i) s += cnt[i];
    sums[t] = s;
    __syncthreads();
    for (int d = 1; d < 1024; d <<= 1) {
        unsigned int v = (t >= d) ? sums[t - d] : 0u;
        __syncthreads();
        sums[t] += v;
        __syncthreads();
    }
    unsigned int run = (t == 0) ? 0u : sums[t - 1];
    for (int i = lo; i < hi; ++i) { off[i] = run; run += cnt[i]; }
}

__global__ void k_fill(const unsigned int* __restrict__ off, unsigned int* __restrict__ cur,
                       unsigned int* __restrict__ list, int N) {
    int n = blockIdx.x * 256 + threadIdx.x;
    if (n < N) { unsigned int o = off[n]; list[o] = (unsigned int)n; cur[n] = o + 1u; }
}

__global__ void k_scatter(const int* __restrict__ ei, int E,
                          unsigned int* __restrict__ cur, unsigned int* __restrict__ list) {
    int e = blockIdx.x * 256 + threadIdx.x;
    if (e < E) {
        int d = ei[E + e];
        unsigned int p = atomicAdd(&cur[d], 1u);
        list[p] = (unsigned int)ei[e];
    }
}

// ===================== edge kernel: one wave per dst (unchanged from R5) =====================
static __device__ __forceinline__ float rl(float v, int l) {
    return __int_as_float(__builtin_amdgcn_readlane(__float_as_int(v), l));
}

#define TPB_E 256
#define EDGE_WPB 4
__global__ __launch_bounds__(TPB_E, 3) void edge_kernel(
    const float* __restrict__ x, const float* __restrict__ pos,
    const unsigned int* __restrict__ off, const unsigned int* __restrict__ cur,
    const unsigned int* __restrict__ list,
    const float* __restrict__ W1, const float* __restrict__ b1,
    const float* __restrict__ W2, const float* __restrict__ b2,
    float* __restrict__ agg, int N, int dstStride)
{
    int lane = threadIdx.x & 63;
    int dst0 = blockIdx.x * EDGE_WPB + (threadIdx.x >> 6);

    float w1c[6];
#pragma unroll
    for (int k = 0; k < 6; ++k) w1c[k] = W1[k * 64 + lane];
    float b1c = b1[lane], b2c = b2[lane];
    float w2c[64];
#pragma unroll
    for (int j = 0; j < 64; ++j) w2c[j] = W2[j * 64 + lane];
#pragma unroll
    for (int k = 0; k < 6; ++k) asm volatile("" : "+v"(w1c[k]));
#pragma unroll
    for (int j = 0; j < 64; ++j) asm volatile("" : "+v"(w2c[j]));

    for (int dst = dst0; dst < N; dst += dstStride) {
        unsigned int o0 = off[dst];
        int cnt = (int)(cur[dst] - o0);
        float pi0 = pos[dst * 3 + 0], pi1 = pos[dst * 3 + 1], pi2 = pos[dst * 3 + 2];
        float m = -INFINITY;

        float in0 = 0.f, in1 = 0.f, in2 = 0.f, in3 = 0.f, in4 = 0.f, in5 = 0.f;
        if (lane < 8) {
            int i = lane;
            int s = (i < cnt) ? (int)list[o0 + i] : dst;
            in0 = x[s * 3 + 0]; in1 = x[s * 3 + 1]; in2 = x[s * 3 + 2];
            in3 = pos[s * 3 + 0] - pi0; in4 = pos[s * 3 + 1] - pi1; in5 = pos[s * 3 + 2] - pi2;
        }

        for (int base = 0; base < cnt; base += 8) {
            int nb = min(8, cnt - base);
            float n0 = 0.f, n1 = 0.f, n2 = 0.f, n3 = 0.f, n4 = 0.f, n5 = 0.f;
            if (lane < 8 && base + 8 < cnt) {
                int i = base + 8 + lane;
                int s = (i < cnt) ? (int)list[o0 + i] : dst;
                n0 = x[s * 3 + 0]; n1 = x[s * 3 + 1]; n2 = x[s * 3 + 2];
                n3 = pos[s * 3 + 0] - pi0; n4 = pos[s * 3 + 1] - pi1; n5 = pos[s * 3 + 2] - pi2;
            }
            float h[8];
#pragma unroll
            for (int e = 0; e < 8; ++e) {
                float t = b1c;
                t = fmaf(rl(in0, e), w1c[0], t);
                t = fmaf(rl(in1, e), w1c[1], t);
                t = fmaf(rl(in2, e), w1c[2], t);
                t = fmaf(rl(in3, e), w1c[3], t);
                t = fmaf(rl(in4, e), w1c[4], t);
                t = fmaf(rl(in5, e), w1c[5], t);
                h[e] = fmaxf(t, 0.f);
            }
#pragma unroll
            for (int e = 0; e < 8; ++e) {
                if (e >= nb) break;
                int hh = __float_as_int(h[e]);
                float t0 = b2c, t1 = 0.f, t2 = 0.f, t3 = 0.f;
#pragma unroll
                for (int j = 0; j < 64; j += 4) {
                    t0 = fmaf(__int_as_float(__builtin_amdgcn_readlane(hh, j + 0)), w2c[j + 0], t0);
                    t1 = fmaf(__int_as_float(__builtin_amdgcn_readlane(hh, j + 1)), w2c[j + 1], t1);
                    t2 = fmaf(__int_as_float(__builtin_amdgcn_readlane(hh, j + 2)), w2c[j + 2], t2);
                    t3 = fmaf(__int_as_float(__builtin_amdgcn_readlane(hh, j + 3)), w2c[j + 3], t3);
                }
                m = fmaxf(m, (t0 + t1) + (t2 + t3));
            }
            in0 = n0; in1 = n1; in2 = n2; in3 = n3; in4 = n4; in5 = n5;
        }
        agg[(size_t)dst * 64 + lane] = m;
    }
}

// ===================== node kernel: fused GEMM chain, 32 nodes/block =====================
// R5 lesson: LDS pipe (1 per CU, shared by 4 SIMDs) was 2.9x oversubscribed by
// scalar ds_read_b32 -> VALUBusy 30%. Fix: all activation reads are ds_read_b128
// covering 4 k-steps, amortized over 8-wide (L4) / 4-wide (L5) column tiles.
// LDS row stride 132 (=4 mod 32): the 4 node-broadcast addresses per read land
// in different banks. Accumulator tiles <=16 floats (anti-spill invariant).
#define NODES 32
static __device__ __forceinline__ float f4i(const float4& v, int kk) {
    switch (kk) { case 0: return v.x; case 1: return v.y; case 2: return v.z; default: return v.w; }
}

__global__ __launch_bounds__(256, 3) void node_kernel(
    const float* __restrict__ agg,
    const float* __restrict__ W3, const float* __restrict__ b3,
    const float* __restrict__ W4, const float* __restrict__ b4,
    const float* __restrict__ W5, const float* __restrict__ b5,
    const float* __restrict__ Wf, const float* __restrict__ bf,
    float* __restrict__ out, int N)
{
    __shared__ float smem[2048 + 4224 + 4224];   // 41 KB -> 3 blocks/CU
    float* As  = smem;                 // [32][64] agg staging
    float* G3s = smem;                 // [32][64] (reuse: As dead after L3)
    float* G1s = smem + 2048;          // [32][132]
    float* G2s = smem + 2048 + 4224;   // [32][132]
    float* os  = G2s;                  // [32][40]  (reuse: G2s dead after last chunk)

    int tid = threadIdx.x;
    int n0 = blockIdx.x * NODES;

    // ---- stage agg tile (coalesced float4, clamped) ----
    {
        int v = tid;                        // float4 index 0..511
        int node = v >> 4, kpos = (v & 15) * 4;
        int src = min(n0 + node, N - 1);
        *(float4*)&As[node * 64 + kpos] = *(const float4*)(agg + (size_t)src * 64 + kpos);
        v = tid + 256;
        node = v >> 4; kpos = (v & 15) * 4;
        src = min(n0 + node, N - 1);
        *(float4*)&As[node * 64 + kpos] = *(const float4*)(agg + (size_t)src * 64 + kpos);
    }
    __syncthreads();

    // ---- L3: g1[32][128] = relu(agg @ W3 + b3). thread: 4 nodes x 4 cols ----
    {
        int cg = tid & 31, q = tid >> 5;
        int col = cg * 4;
        float acc[4][4];
        float4 bv = *(const float4*)(b3 + col);
#pragma unroll
        for (int j = 0; j < 4; ++j) { acc[j][0] = bv.x; acc[j][1] = bv.y; acc[j][2] = bv.z; acc[j][3] = bv.w; }
        for (int k = 0; k < 64; k += 4) {
            float4 aa0 = *(const float4*)&As[(q * 4 + 0) * 64 + k];
            float4 aa1 = *(const float4*)&As[(q * 4 + 1) * 64 + k];
            float4 aa2 = *(const float4*)&As[(q * 4 + 2) * 64 + k];
            float4 aa3 = *(const float4*)&As[(q * 4 + 3) * 64 + k];
#pragma unroll
            for (int kk = 0; kk < 4; ++kk) {
                float4 wv = *(const float4*)(W3 + (k + kk) * 128 + col);
                float a0 = f4i(aa0, kk), a1 = f4i(aa1, kk), a2 = f4i(aa2, kk), a3 = f4i(aa3, kk);
                acc[0][0] = fmaf(a0, wv.x, acc[0][0]); acc[0][1] = fmaf(a0, wv.y, acc[0][1]);
                acc[0][2] = fmaf(a0, wv.z, acc[0][2]); acc[0][3] = fmaf(a0, wv.w, acc[0][3]);
                acc[1][0] = fmaf(a1, wv.x, acc[1][0]); acc[1][1] = fmaf(a1, wv.y, acc[1][1]);
                acc[1][2] = fmaf(a1, wv.z, acc[1][2]); acc[1][3] = fmaf(a1, wv.w, acc[1][3]);
                acc[2][0] = fmaf(a2, wv.x, acc[2][0]); acc[2][1] = fmaf(a2, wv.y, acc[2][1]);
                acc[2][2] = fmaf(a2, wv.z, acc[2][2]); acc[2][3] = fmaf(a2, wv.w, acc[2][3]);
                acc[3][0] = fmaf(a3, wv.x, acc[3][0]); acc[3][1] = fmaf(a3, wv.y, acc[3][1]);
                acc[3][2] = fmaf(a3, wv.z, acc[3][2]); acc[3][3] = fmaf(a3, wv.w, acc[3][3]);
            }
        }
#pragma unroll
        for (int j = 0; j < 4; ++j) {
            *(float4*)&G1s[(q * 4 + j) * 132 + col] = make_float4(
                fmaxf(acc[j][0], 0.f), fmaxf(acc[j][1], 0.f),
                fmaxf(acc[j][2], 0.f), fmaxf(acc[j][3], 0.f));
        }
    }
    __syncthreads();

    // ---- L4+L5 fused over 8 chunks of 128 g2-channels ----
    int cg = tid & 15;          // 16 col groups
    int ng = tid >> 4;          // 16 node pairs
    int nA = ng * 2, nB = nA + 1;
    int col8 = cg * 8;          // L4: 8 cols within chunk
    int col4 = cg * 4;          // L5: 4 out cols of 64

    float g3[2][4];
    {
        float4 bv = *(const float4*)(b5 + col4);
        g3[0][0] = bv.x; g3[0][1] = bv.y; g3[0][2] = bv.z; g3[0][3] = bv.w;
        g3[1][0] = bv.x; g3[1][1] = bv.y; g3[1][2] = bv.z; g3[1][3] = bv.w;
    }

    for (int ch = 0; ch < 8; ++ch) {
        // L4: g2 tile 2 nodes x 8 cols
        float t[2][8];
        {
            float4 b0 = *(const float4*)(b4 + ch * 128 + col8);
            float4 b1v = *(const float4*)(b4 + ch * 128 + col8 + 4);
            t[0][0] = b0.x; t[0][1] = b0.y; t[0][2] = b0.z; t[0][3] = b0.w;
            t[0][4] = b1v.x; t[0][5] = b1v.y; t[0][6] = b1v.z; t[0][7] = b1v.w;
#pragma unroll
            for (int q = 0; q < 8; ++q) t[1][q] = t[0][q];
        }
        for (int k = 0; k < 128; k += 4) {
            float4 aA = *(const float4*)&G1s[nA * 132 + k];
            float4 aB = *(const float4*)&G1s[nB * 132 + k];
            const float* wb = W4 + (size_t)k * 1024 + ch * 128 + col8;
#pragma unroll
            for (int kk = 0; kk < 4; ++kk) {
                float4 w0 = *(const float4*)(wb + (size_t)kk * 1024);
                float4 w1 = *(const float4*)(wb + (size_t)kk * 1024 + 4);
                float fA = f4i(aA, kk), fB = f4i(aB, kk);
                t[0][0] = fmaf(fA, w0.x, t[0][0]); t[0][1] = fmaf(fA, w0.y, t[0][1]);
                t[0][2] = fmaf(fA, w0.z, t[0][2]); t[0][3] = fmaf(fA, w0.w, t[0][3]);
                t[0][4] = fmaf(fA, w1.x, t[0][4]); t[0][5] = fmaf(fA, w1.y, t[0][5]);
                t[0][6] = fmaf(fA, w1.z, t[0][6]); t[0][7] = fmaf(fA, w1.w, t[0][7]);
                t[1][0] = fmaf(fB, w0.x, t[1][0]); t[1][1] = fmaf(fB, w0.y, t[1][1]);
                t[1][2] = fmaf(fB, w0.z, t[1][2]); t[1][3] = fmaf(fB, w0.w, t[1][3]);
                t[1][4] = fmaf(fB, w1.x, t[1][4]); t[1][5] = fmaf(fB, w1.y, t[1][5]);
                t[1][6] = fmaf(fB, w1.z, t[1][6]); t[1][7] = fmaf(fB, w1.w, t[1][7]);
            }
        }
        // relu + write g2 chunk
        *(float4*)&G2s[nA * 132 + col8] = make_float4(
            fmaxf(t[0][0], 0.f), fmaxf(t[0][1], 0.f), fmaxf(t[0][2], 0.f), fmaxf(t[0][3], 0.f));
        *(float4*)&G2s[nA * 132 + col8 + 4] = make_float4(
            fmaxf(t[0][4], 0.f), fmaxf(t[0][5], 0.f), fmaxf(t[0][6], 0.f), fmaxf(t[0][7], 0.f));
        *(float4*)&G2s[nB * 132 + col8] = make_float4(
            fmaxf(t[1][0], 0.f), fmaxf(t[1][1], 0.f), fmaxf(t[1][2], 0.f), fmaxf(t[1][3], 0.f));
        *(float4*)&G2s[nB * 132 + col8 + 4] = make_float4(
            fmaxf(t[1][4], 0.f), fmaxf(t[1][5], 0.f), fmaxf(t[1][6], 0.f), fmaxf(t[1][7], 0.f));
        __syncthreads();

        // L5: accumulate g3 over this chunk's 128 channels
        for (int k = 0; k < 128; k += 4) {
            float4 gA = *(const float4*)&G2s[nA * 132 + k];
            float4 gB = *(const float4*)&G2s[nB * 132 + k];
#pragma unroll
            for (int kk = 0; kk < 4; ++kk) {
                float4 wv = *(const float4*)(W5 + (size_t)(ch * 128 + k + kk) * 64 + col4);
                float fA = f4i(gA, kk), fB = f4i(gB, kk);
                g3[0][0] = fmaf(fA, wv.x, g3[0][0]); g3[0][1] = fmaf(fA, wv.y, g3[0][1]);
                g3[0][2] = fmaf(fA, wv.z, g3[0][2]); g3[0][3] = fmaf(fA, wv.w, g3[0][3]);
                g3[1][0] = fmaf(fB, wv.x, g3[1][0]); g3[1][1] = fmaf(fB, wv.y, g3[1][1]);
                g3[1][2] = fmaf(fB, wv.z, g3[1][2]); g3[1][3] = fmaf(fB, wv.w, g3[1][3]);
            }
        }
        __syncthreads();   // guard next chunk's G2s overwrite
    }

    // ---- stage relu(g3) into As region (dead since L3) ----
    *(float4*)&G3s[nA * 64 + col4] = make_float4(
        fmaxf(g3[0][0], 0.f), fmaxf(g3[0][1], 0.f), fmaxf(g3[0][2], 0.f), fmaxf(g3[0][3], 0.f));
    *(float4*)&G3s[nB * 64 + col4] = make_float4(
        fmaxf(g3[1][0], 0.f), fmaxf(g3[1][1], 0.f), fmaxf(g3[1][2], 0.f), fmaxf(g3[1][3], 0.f));
    __syncthreads();

    // ---- fc: 32 nodes x 40 outputs (os reuses G2s region) ----
    for (int idx = tid; idx < NODES * 40; idx += 256) {
        int ln = idx / 40;
        int c = idx - ln * 40;
        float o = bf[c];
#pragma unroll 4
        for (int j = 0; j < 64; ++j)
            o = fmaf(G3s[ln * 64 + j], Wf[j * 40 + c], o);
        os[ln * 40 + c] = o;
    }
    __syncthreads();

    // ---- log_softmax + store ----
    if (tid < NODES && n0 + tid < N) {
        int ln = tid;
        float mx = os[ln * 40 + 0];
#pragma unroll
        for (int c = 1; c < 40; ++c) mx = fmaxf(mx, os[ln * 40 + c]);
        float s = 0.f;
#pragma unroll
        for (int c = 0; c < 40; ++c) s += expf(os[ln * 40 + c] - mx);
        float ls = logf(s) + mx;
        float* op = out + (size_t)(n0 + ln) * 40;
#pragma unroll
        for (int c = 0; c < 40; ++c) op[c] = os[ln * 40 + c] - ls;
    }
}

// ============================ launch ============================
extern "C" void kernel_launch(void* const* d_in, const int* in_sizes, int n_in,
                              void* d_out, int out_size, void* d_ws, size_t ws_size,
                              hipStream_t stream) {
    const float* x   = (const float*)d_in[0];
    const float* pos = (const float*)d_in[1];
    const int*   ei  = (const int*)d_in[2];
    const float* W1  = (const float*)d_in[3];
    const float* b1  = (const float*)d_in[4];
    const float* W2  = (const float*)d_in[5];
    const float* b2  = (const float*)d_in[6];
    const float* W3  = (const float*)d_in[7];
    const float* b3  = (const float*)d_in[8];
    const float* W4  = (const float*)d_in[9];
    const float* b4  = (const float*)d_in[10];
    const float* W5  = (const float*)d_in[11];
    const float* b5  = (const float*)d_in[12];
    const float* Wf  = (const float*)d_in[13];
    const float* bf  = (const float*)d_in[14];
    float* out = (float*)d_out;

    int Nn = in_sizes[0] / 3;   // 50000
    int E  = in_sizes[2] / 2;   // 1600000

    char* w = (char*)d_ws;
    size_t p = 0;
    auto take = [&](size_t bytes) { size_t q = p; p = (p + bytes + 255) & ~size_t(255); return (void*)(w + q); };
    unsigned int* off  = (unsigned int*)take((size_t)Nn * 4);
    unsigned int* cnt  = (unsigned int*)take((size_t)Nn * 4);   // reused as cursor
    unsigned int* list = (unsigned int*)take((size_t)(E + Nn) * 4);
    float*        agg  = (float*)take((size_t)Nn * 64 * 4);

    k_init_cnt<<<(Nn + 255) / 256, 256, 0, stream>>>(cnt, Nn);
    k_count<<<(E + 255) / 256, 256, 0, stream>>>(ei, E, cnt);
    k_scan<<<1, 1024, 0, stream>>>(cnt, off, Nn);
    k_fill<<<(Nn + 255) / 256, 256, 0, stream>>>(off, cnt, list, Nn);
    k_scatter<<<(E + 255) / 256, 256, 0, stream>>>(ei, E, cnt, list);

    int totalWaves = (Nn + 3) / 4;
    int eBlocks = (totalWaves + EDGE_WPB - 1) / EDGE_WPB;
    int dstStride = eBlocks * EDGE_WPB;
    edge_kernel<<<eBlocks, TPB_E, 0, stream>>>(
        x, pos, off, cnt, list, W1, b1, W2, b2, agg, Nn, dstStride);

    node_kernel<<<(Nn + NODES - 1) / NODES, 256, 0, stream>>>(
        agg, W3, b3, W4, b4, W5, b5, Wf, bf, out, Nn);
}

// Round 7
// 1249.594 us; speedup vs baseline: 1.1092x; 1.1092x over previous
//
#include <hip/hip_runtime.h>
#include <cstddef>
#include <cmath>

// ============================ CSR build ============================
__global__ void k_init_cnt(unsigned int* __restrict__ cnt, int N) {
    int i = blockIdx.x * 256 + threadIdx.x;
    if (i < N) cnt[i] = 1u;   // self-loop pre-counted
}

__global__ void k_count(const int* __restrict__ ei, int E, unsigned int* __restrict__ cnt) {
    int e = blockIdx.x * 256 + threadIdx.x;
    if (e < E) atomicAdd(&cnt[ei[E + e]], 1u);
}

__global__ __launch_bounds__(1024) void k_scan(const unsigned int* __restrict__ cnt,
                                               unsigned int* __restrict__ off, int N) {
    __shared__ unsigned int sums[1024];
    int t = threadIdx.x;
    int chunk = (N + 1023) >> 10;
    int lo = t * chunk, hi = min(lo + chunk, N);
    unsigned int s = 0;
    for (int i = lo; i < hi; ++i) s += cnt[i];
    sums[t] = s;
    __syncthreads();
    for (int d = 1; d < 1024; d <<= 1) {
        unsigned int v = (t >= d) ? sums[t - d] : 0u;
        __syncthreads();
        sums[t] += v;
        __syncthreads();
    }
    unsigned int run = (t == 0) ? 0u : sums[t - 1];
    for (int i = lo; i < hi; ++i) { off[i] = run; run += cnt[i]; }
}

__global__ void k_fill(const unsigned int* __restrict__ off, unsigned int* __restrict__ cur,
                       unsigned int* __restrict__ list, int N) {
    int n = blockIdx.x * 256 + threadIdx.x;
    if (n < N) { unsigned int o = off[n]; list[o] = (unsigned int)n; cur[n] = o + 1u; }
}

__global__ void k_scatter(const int* __restrict__ ei, int E,
                          unsigned int* __restrict__ cur, unsigned int* __restrict__ list) {
    int e = blockIdx.x * 256 + threadIdx.x;
    if (e < E) {
        int d = ei[E + e];
        unsigned int p = atomicAdd(&cur[d], 1u);
        list[p] = (unsigned int)ei[e];
    }
}

// ===================== edge kernel: one wave per dst (unchanged) =====================
static __device__ __forceinline__ float rl(float v, int l) {
    return __int_as_float(__builtin_amdgcn_readlane(__float_as_int(v), l));
}

#define TPB_E 256
#define EDGE_WPB 4
__global__ __launch_bounds__(TPB_E, 3) void edge_kernel(
    const float* __restrict__ x, const float* __restrict__ pos,
    const unsigned int* __restrict__ off, const unsigned int* __restrict__ cur,
    const unsigned int* __restrict__ list,
    const float* __restrict__ W1, const float* __restrict__ b1,
    const float* __restrict__ W2, const float* __restrict__ b2,
    float* __restrict__ agg, int N, int dstStride)
{
    int lane = threadIdx.x & 63;
    int dst0 = blockIdx.x * EDGE_WPB + (threadIdx.x >> 6);

    float w1c[6];
#pragma unroll
    for (int k = 0; k < 6; ++k) w1c[k] = W1[k * 64 + lane];
    float b1c = b1[lane], b2c = b2[lane];
    float w2c[64];
#pragma unroll
    for (int j = 0; j < 64; ++j) w2c[j] = W2[j * 64 + lane];
#pragma unroll
    for (int k = 0; k < 6; ++k) asm volatile("" : "+v"(w1c[k]));
#pragma unroll
    for (int j = 0; j < 64; ++j) asm volatile("" : "+v"(w2c[j]));

    for (int dst = dst0; dst < N; dst += dstStride) {
        unsigned int o0 = off[dst];
        int cnt = (int)(cur[dst] - o0);
        float pi0 = pos[dst * 3 + 0], pi1 = pos[dst * 3 + 1], pi2 = pos[dst * 3 + 2];
        float m = -INFINITY;

        float in0 = 0.f, in1 = 0.f, in2 = 0.f, in3 = 0.f, in4 = 0.f, in5 = 0.f;
        if (lane < 8) {
            int i = lane;
            int s = (i < cnt) ? (int)list[o0 + i] : dst;
            in0 = x[s * 3 + 0]; in1 = x[s * 3 + 1]; in2 = x[s * 3 + 2];
            in3 = pos[s * 3 + 0] - pi0; in4 = pos[s * 3 + 1] - pi1; in5 = pos[s * 3 + 2] - pi2;
        }

        for (int base = 0; base < cnt; base += 8) {
            int nb = min(8, cnt - base);
            float n0 = 0.f, n1 = 0.f, n2 = 0.f, n3 = 0.f, n4 = 0.f, n5 = 0.f;
            if (lane < 8 && base + 8 < cnt) {
                int i = base + 8 + lane;
                int s = (i < cnt) ? (int)list[o0 + i] : dst;
                n0 = x[s * 3 + 0]; n1 = x[s * 3 + 1]; n2 = x[s * 3 + 2];
                n3 = pos[s * 3 + 0] - pi0; n4 = pos[s * 3 + 1] - pi1; n5 = pos[s * 3 + 2] - pi2;
            }
            float h[8];
#pragma unroll
            for (int e = 0; e < 8; ++e) {
                float t = b1c;
                t = fmaf(rl(in0, e), w1c[0], t);
                t = fmaf(rl(in1, e), w1c[1], t);
                t = fmaf(rl(in2, e), w1c[2], t);
                t = fmaf(rl(in3, e), w1c[3], t);
                t = fmaf(rl(in4, e), w1c[4], t);
                t = fmaf(rl(in5, e), w1c[5], t);
                h[e] = fmaxf(t, 0.f);
            }
#pragma unroll
            for (int e = 0; e < 8; ++e) {
                if (e >= nb) break;
                int hh = __float_as_int(h[e]);
                float t0 = b2c, t1 = 0.f, t2 = 0.f, t3 = 0.f;
#pragma unroll
                for (int j = 0; j < 64; j += 4) {
                    t0 = fmaf(__int_as_float(__builtin_amdgcn_readlane(hh, j + 0)), w2c[j + 0], t0);
                    t1 = fmaf(__int_as_float(__builtin_amdgcn_readlane(hh, j + 1)), w2c[j + 1], t1);
                    t2 = fmaf(__int_as_float(__builtin_amdgcn_readlane(hh, j + 2)), w2c[j + 2], t2);
                    t3 = fmaf(__int_as_float(__builtin_amdgcn_readlane(hh, j + 3)), w2c[j + 3], t3);
                }
                m = fmaxf(m, (t0 + t1) + (t2 + t3));
            }
            in0 = n0; in1 = n1; in2 = n2; in3 = n3; in4 = n4; in5 = n5;
        }
        agg[(size_t)dst * 64 + lane] = m;
    }
}

// ===================== node kernel: fused GEMM chain, 32 nodes/block =====================
// R6 lesson: VMEM-path-bound (R5 vs R6: different LDS behavior, identical time).
// Fix: 4-node x 4-col thread tiles -> one coalesced weight float4 feeds 16 FMA
// (2x fewer weight loads, 512B/instr across 32 lanes); L5 k-split across thread
// halves keeps the ratio; LDS down to 33KB -> 4 blocks/CU. Acc tiles <=16 floats.
#define NODES 32
static __device__ __forceinline__ float f4i(const float4& v, int kk) {
    switch (kk) { case 0: return v.x; case 1: return v.y; case 2: return v.z; default: return v.w; }
}

__global__ __launch_bounds__(256, 4) void node_kernel(
    const float* __restrict__ agg,
    const float* __restrict__ W3, const float* __restrict__ b3,
    const float* __restrict__ W4, const float* __restrict__ b4,
    const float* __restrict__ W5, const float* __restrict__ b5,
    const float* __restrict__ Wf, const float* __restrict__ bf,
    float* __restrict__ out, int N)
{
    __shared__ float smem[4224 * 2];     // 33 KB -> 4 blocks/CU
    float* R0 = smem;                    // As[32][64] -> G2s[32][132] -> G3s[32][68]
    float* R1 = smem + 4224;             // G1s[32][132] -> g3 partials[32][68] -> os[32][40]

    int tid = threadIdx.x;
    int n0 = blockIdx.x * NODES;

    // ---- stage agg tile (coalesced float4, clamped) ----
    {
        int v = tid;
        int node = v >> 4, kpos = (v & 15) * 4;
        int src = min(n0 + node, N - 1);
        *(float4*)&R0[node * 64 + kpos] = *(const float4*)(agg + (size_t)src * 64 + kpos);
        v = tid + 256;
        node = v >> 4; kpos = (v & 15) * 4;
        src = min(n0 + node, N - 1);
        *(float4*)&R0[node * 64 + kpos] = *(const float4*)(agg + (size_t)src * 64 + kpos);
    }
    __syncthreads();

    // ---- L3: g1[32][128] = relu(agg @ W3 + b3). thread: 4 nodes x 4 cols ----
    {
        int col = (tid & 31) * 4;
        int q = tid >> 5;
        float acc[4][4];
        float4 bv = *(const float4*)(b3 + col);
#pragma unroll
        for (int j = 0; j < 4; ++j) { acc[j][0] = bv.x; acc[j][1] = bv.y; acc[j][2] = bv.z; acc[j][3] = bv.w; }
        for (int k = 0; k < 64; k += 4) {
            float4 a0 = *(const float4*)&R0[(q * 4 + 0) * 64 + k];
            float4 a1 = *(const float4*)&R0[(q * 4 + 1) * 64 + k];
            float4 a2 = *(const float4*)&R0[(q * 4 + 2) * 64 + k];
            float4 a3 = *(const float4*)&R0[(q * 4 + 3) * 64 + k];
#pragma unroll
            for (int kk = 0; kk < 4; ++kk) {
                float4 wv = *(const float4*)(W3 + (size_t)(k + kk) * 128 + col);
                float v0 = f4i(a0, kk), v1 = f4i(a1, kk), v2 = f4i(a2, kk), v3 = f4i(a3, kk);
                acc[0][0] = fmaf(v0, wv.x, acc[0][0]); acc[0][1] = fmaf(v0, wv.y, acc[0][1]);
                acc[0][2] = fmaf(v0, wv.z, acc[0][2]); acc[0][3] = fmaf(v0, wv.w, acc[0][3]);
                acc[1][0] = fmaf(v1, wv.x, acc[1][0]); acc[1][1] = fmaf(v1, wv.y, acc[1][1]);
                acc[1][2] = fmaf(v1, wv.z, acc[1][2]); acc[1][3] = fmaf(v1, wv.w, acc[1][3]);
                acc[2][0] = fmaf(v2, wv.x, acc[2][0]); acc[2][1] = fmaf(v2, wv.y, acc[2][1]);
                acc[2][2] = fmaf(v2, wv.z, acc[2][2]); acc[2][3] = fmaf(v2, wv.w, acc[2][3]);
                acc[3][0] = fmaf(v3, wv.x, acc[3][0]); acc[3][1] = fmaf(v3, wv.y, acc[3][1]);
                acc[3][2] = fmaf(v3, wv.z, acc[3][2]); acc[3][3] = fmaf(v3, wv.w, acc[3][3]);
            }
        }
#pragma unroll
        for (int j = 0; j < 4; ++j) {
            *(float4*)&R1[(q * 4 + j) * 132 + col] = make_float4(
                fmaxf(acc[j][0], 0.f), fmaxf(acc[j][1], 0.f),
                fmaxf(acc[j][2], 0.f), fmaxf(acc[j][3], 0.f));
        }
    }
    __syncthreads();

    // ---- L4+L5 fused over 8 chunks of 128 g2-channels ----
    // L4 mapping: cgA=tid&31 (col=cgA*4 in chunk), ngA=tid>>5 (nodes ngA*4..+4)
    // L5 mapping: cgB=tid&15 (outcol=cgB*4), ngB=tid>>4; nodes (ngB&7)*4..+4,
    //             k-half = ngB>>3 (k in [kh*64, kh*64+64) of the chunk)
    int cgA = tid & 31, ngA = tid >> 5;
    int colA = cgA * 4;
    int cgB = tid & 15, ngB = tid >> 4;
    int colB = cgB * 4;
    int nbase = (ngB & 7) * 4;
    int kh0 = (ngB >> 3) * 64;

    float g3[4][4];
    {
        float4 bv = *(const float4*)(b5 + colB);
#pragma unroll
        for (int j = 0; j < 4; ++j) {
            g3[j][0] = (ngB < 8) ? bv.x : 0.f; g3[j][1] = (ngB < 8) ? bv.y : 0.f;
            g3[j][2] = (ngB < 8) ? bv.z : 0.f; g3[j][3] = (ngB < 8) ? bv.w : 0.f;
        }
    }

    for (int ch = 0; ch < 8; ++ch) {
        // ---- L4: g2 chunk tile 4 nodes x 4 cols ----
        float t[4][4];
        {
            float4 bv = *(const float4*)(b4 + ch * 128 + colA);
#pragma unroll
            for (int j = 0; j < 4; ++j) { t[j][0] = bv.x; t[j][1] = bv.y; t[j][2] = bv.z; t[j][3] = bv.w; }
        }
        for (int k = 0; k < 128; k += 4) {
            float4 a0 = *(const float4*)&R1[(ngA * 4 + 0) * 132 + k];
            float4 a1 = *(const float4*)&R1[(ngA * 4 + 1) * 132 + k];
            float4 a2 = *(const float4*)&R1[(ngA * 4 + 2) * 132 + k];
            float4 a3 = *(const float4*)&R1[(ngA * 4 + 3) * 132 + k];
            const float* wb = W4 + (size_t)k * 1024 + ch * 128 + colA;
#pragma unroll
            for (int kk = 0; kk < 4; ++kk) {
                float4 wv = *(const float4*)(wb + (size_t)kk * 1024);
                float v0 = f4i(a0, kk), v1 = f4i(a1, kk), v2 = f4i(a2, kk), v3 = f4i(a3, kk);
                t[0][0] = fmaf(v0, wv.x, t[0][0]); t[0][1] = fmaf(v0, wv.y, t[0][1]);
                t[0][2] = fmaf(v0, wv.z, t[0][2]); t[0][3] = fmaf(v0, wv.w, t[0][3]);
                t[1][0] = fmaf(v1, wv.x, t[1][0]); t[1][1] = fmaf(v1, wv.y, t[1][1]);
                t[1][2] = fmaf(v1, wv.z, t[1][2]); t[1][3] = fmaf(v1, wv.w, t[1][3]);
                t[2][0] = fmaf(v2, wv.x, t[2][0]); t[2][1] = fmaf(v2, wv.y, t[2][1]);
                t[2][2] = fmaf(v2, wv.z, t[2][2]); t[2][3] = fmaf(v2, wv.w, t[2][3]);
                t[3][0] = fmaf(v3, wv.x, t[3][0]); t[3][1] = fmaf(v3, wv.y, t[3][1]);
                t[3][2] = fmaf(v3, wv.z, t[3][2]); t[3][3] = fmaf(v3, wv.w, t[3][3]);
            }
        }
#pragma unroll
        for (int j = 0; j < 4; ++j) {
            *(float4*)&R0[(ngA * 4 + j) * 132 + colA] = make_float4(
                fmaxf(t[j][0], 0.f), fmaxf(t[j][1], 0.f), fmaxf(t[j][2], 0.f), fmaxf(t[j][3], 0.f));
        }
        __syncthreads();

        // ---- L5: accumulate my k-half of this chunk ----
        for (int k = kh0; k < kh0 + 64; k += 4) {
            float4 a0 = *(const float4*)&R0[(nbase + 0) * 132 + k];
            float4 a1 = *(const float4*)&R0[(nbase + 1) * 132 + k];
            float4 a2 = *(const float4*)&R0[(nbase + 2) * 132 + k];
            float4 a3 = *(const float4*)&R0[(nbase + 3) * 132 + k];
#pragma unroll
            for (int kk = 0; kk < 4; ++kk) {
                float4 wv = *(const float4*)(W5 + (size_t)(ch * 128 + k + kk) * 64 + colB);
                float v0 = f4i(a0, kk), v1 = f4i(a1, kk), v2 = f4i(a2, kk), v3 = f4i(a3, kk);
                g3[0][0] = fmaf(v0, wv.x, g3[0][0]); g3[0][1] = fmaf(v0, wv.y, g3[0][1]);
                g3[0][2] = fmaf(v0, wv.z, g3[0][2]); g3[0][3] = fmaf(v0, wv.w, g3[0][3]);
                g3[1][0] = fmaf(v1, wv.x, g3[1][0]); g3[1][1] = fmaf(v1, wv.y, g3[1][1]);
                g3[1][2] = fmaf(v1, wv.z, g3[1][2]); g3[1][3] = fmaf(v1, wv.w, g3[1][3]);
                g3[2][0] = fmaf(v2, wv.x, g3[2][0]); g3[2][1] = fmaf(v2, wv.y, g3[2][1]);
                g3[2][2] = fmaf(v2, wv.z, g3[2][2]); g3[2][3] = fmaf(v2, wv.w, g3[2][3]);
                g3[3][0] = fmaf(v3, wv.x, g3[3][0]); g3[3][1] = fmaf(v3, wv.y, g3[3][1]);
                g3[3][2] = fmaf(v3, wv.z, g3[3][2]); g3[3][3] = fmaf(v3, wv.w, g3[3][3]);
            }
        }
        __syncthreads();   // guard next chunk's G2s overwrite
    }

    // ---- reduce k-halves: high half writes partials into R1 (G1s dead) ----
    if (ngB >= 8) {
#pragma unroll
        for (int j = 0; j < 4; ++j)
            *(float4*)&R1[(nbase + j) * 68 + colB] = make_float4(g3[j][0], g3[j][1], g3[j][2], g3[j][3]);
    }
    __syncthreads();
    if (ngB < 8) {
#pragma unroll
        for (int j = 0; j < 4; ++j) {
            float4 p = *(const float4*)&R1[(nbase + j) * 68 + colB];
            *(float4*)&R0[(nbase + j) * 68 + colB] = make_float4(
                fmaxf(g3[j][0] + p.x, 0.f), fmaxf(g3[j][1] + p.y, 0.f),
                fmaxf(g3[j][2] + p.z, 0.f), fmaxf(g3[j][3] + p.w, 0.f));
        }
    }
    __syncthreads();

    // ---- fc: 32 nodes x 40 outputs (G3s in R0 stride 68; os in R1) ----
    for (int idx = tid; idx < NODES * 40; idx += 256) {
        int ln = idx / 40;
        int c = idx - ln * 40;
        float o = bf[c];
#pragma unroll 4
        for (int j = 0; j < 64; ++j)
            o = fmaf(R0[ln * 68 + j], Wf[j * 40 + c], o);
        R1[ln * 40 + c] = o;
    }
    __syncthreads();

    // ---- log_softmax + store ----
    if (tid < NODES && n0 + tid < N) {
        int ln = tid;
        float mx = R1[ln * 40 + 0];
#pragma unroll
        for (int c = 1; c < 40; ++c) mx = fmaxf(mx, R1[ln * 40 + c]);
        float s = 0.f;
#pragma unroll
        for (int c = 0; c < 40; ++c) s += expf(R1[ln * 40 + c] - mx);
        float ls = logf(s) + mx;
        float* op = out + (size_t)(n0 + ln) * 40;
#pragma unroll
        for (int c = 0; c < 40; ++c) op[c] = R1[ln * 40 + c] - ls;
    }
}

// ============================ launch ============================
extern "C" void kernel_launch(void* const* d_in, const int* in_sizes, int n_in,
                              void* d_out, int out_size, void* d_ws, size_t ws_size,
                              hipStream_t stream) {
    const float* x   = (const float*)d_in[0];
    const float* pos = (const float*)d_in[1];
    const int*   ei  = (const int*)d_in[2];
    const float* W1  = (const float*)d_in[3];
    const float* b1  = (const float*)d_in[4];
    const float* W2  = (const float*)d_in[5];
    const float* b2  = (const float*)d_in[6];
    const float* W3  = (const float*)d_in[7];
    const float* b3  = (const float*)d_in[8];
    const float* W4  = (const float*)d_in[9];
    const float* b4  = (const float*)d_in[10];
    const float* W5  = (const float*)d_in[11];
    const float* b5  = (const float*)d_in[12];
    const float* Wf  = (const float*)d_in[13];
    const float* bf  = (const float*)d_in[14];
    float* out = (float*)d_out;

    int Nn = in_sizes[0] / 3;   // 50000
    int E  = in_sizes[2] / 2;   // 1600000

    char* w = (char*)d_ws;
    size_t p = 0;
    auto take = [&](size_t bytes) { size_t q = p; p = (p + bytes + 255) & ~size_t(255); return (void*)(w + q); };
    unsigned int* off  = (unsigned int*)take((size_t)Nn * 4);
    unsigned int* cnt  = (unsigned int*)take((size_t)Nn * 4);   // reused as cursor
    unsigned int* list = (unsigned int*)take((size_t)(E + Nn) * 4);
    float*        agg  = (float*)take((size_t)Nn * 64 * 4);

    k_init_cnt<<<(Nn + 255) / 256, 256, 0, stream>>>(cnt, Nn);
    k_count<<<(E + 255) / 256, 256, 0, stream>>>(ei, E, cnt);
    k_scan<<<1, 1024, 0, stream>>>(cnt, off, Nn);
    k_fill<<<(Nn + 255) / 256, 256, 0, stream>>>(off, cnt, list, Nn);
    k_scatter<<<(E + 255) / 256, 256, 0, stream>>>(ei, E, cnt, list);

    int totalWaves = (Nn + 3) / 4;
    int eBlocks = (totalWaves + EDGE_WPB - 1) / EDGE_WPB;
    int dstStride = eBlocks * EDGE_WPB;
    edge_kernel<<<eBlocks, TPB_E, 0, stream>>>(
        x, pos, off, cnt, list, W1, b1, W2, b2, agg, Nn, dstStride);

    node_kernel<<<(Nn + NODES - 1) / NODES, 256, 0, stream>>>(
        agg, W3, b3, W4, b4, W5, b5, Wf, bf, out, Nn);
}

// Round 8
// 964.568 us; speedup vs baseline: 1.4370x; 1.2955x over previous
//
#include <hip/hip_runtime.h>
#include <cstddef>
#include <cmath>

typedef __attribute__((ext_vector_type(8))) short bf16x8;
typedef __attribute__((ext_vector_type(4))) float f32x4;

static __device__ __forceinline__ f32x4 mfma16(bf16x8 a, bf16x8 b, f32x4 c) {
    return __builtin_amdgcn_mfma_f32_16x16x32_bf16(a, b, c, 0, 0, 0);
}
static __device__ __forceinline__ unsigned short f2bf(float f) {
    unsigned int u = __float_as_uint(f);
    return (unsigned short)((u + 0x7FFFu + ((u >> 16) & 1u)) >> 16);
}

// ============================ CSR build ============================
__global__ void k_init_cnt(unsigned int* __restrict__ cnt, int N) {
    int i = blockIdx.x * 256 + threadIdx.x;
    if (i < N) cnt[i] = 1u;   // self-loop pre-counted
}

__global__ void k_count(const int* __restrict__ ei, int E, unsigned int* __restrict__ cnt) {
    int e = blockIdx.x * 256 + threadIdx.x;
    if (e < E) atomicAdd(&cnt[ei[E + e]], 1u);
}

__global__ __launch_bounds__(1024) void k_scan(const unsigned int* __restrict__ cnt,
                                               unsigned int* __restrict__ off, int N) {
    __shared__ unsigned int sums[1024];
    int t = threadIdx.x;
    int chunk = (N + 1023) >> 10;
    int lo = t * chunk, hi = min(lo + chunk, N);
    unsigned int s = 0;
    for (int i = lo; i < hi; ++i) s += cnt[i];
    sums[t] = s;
    __syncthreads();
    for (int d = 1; d < 1024; d <<= 1) {
        unsigned int v = (t >= d) ? sums[t - d] : 0u;
        __syncthreads();
        sums[t] += v;
        __syncthreads();
    }
    unsigned int run = (t == 0) ? 0u : sums[t - 1];
    for (int i = lo; i < hi; ++i) { off[i] = run; run += cnt[i]; }
}

__global__ void k_fill(const unsigned int* __restrict__ off, unsigned int* __restrict__ cur,
                       unsigned int* __restrict__ list, int N) {
    int n = blockIdx.x * 256 + threadIdx.x;
    if (n < N) { unsigned int o = off[n]; list[o] = (unsigned int)n; cur[n] = o + 1u; }
}

__global__ void k_scatter(const int* __restrict__ ei, int E,
                          unsigned int* __restrict__ cur, unsigned int* __restrict__ list) {
    int e = blockIdx.x * 256 + threadIdx.x;
    if (e < E) {
        int d = ei[E + e];
        unsigned int p = atomicAdd(&cur[d], 1u);
        list[p] = (unsigned int)ei[e];
    }
}

// ============== weight converter: f32 [K][N] -> bf16 transposed [N][K] ==============
__global__ void k_convert(const float* __restrict__ W3, const float* __restrict__ W4,
                          const float* __restrict__ W5,
                          unsigned short* __restrict__ W3bt,
                          unsigned short* __restrict__ W4bt,
                          unsigned short* __restrict__ W5bt) {
    int id = blockIdx.x * 256 + threadIdx.x;
    if (id < 8192) {                       // W3: [64][128] -> [128][64]
        int n = id >> 6, k = id & 63;
        W3bt[id] = f2bf(W3[k * 128 + n]);
    } else if (id < 8192 + 131072) {       // W4: [128][1024] -> [1024][128]
        int t = id - 8192;
        int n = t >> 7, k = t & 127;
        W4bt[t] = f2bf(W4[k * 1024 + n]);
    } else if (id < 8192 + 131072 + 65536) { // W5: [1024][64] -> [64][1024]
        int t = id - 139264;
        int n = t >> 10, k = t & 1023;
        W5bt[t] = f2bf(W5[k * 64 + n]);
    }
}

// ===================== edge kernel: one wave per dst (unchanged from R7) =====================
static __device__ __forceinline__ float rl(float v, int l) {
    return __int_as_float(__builtin_amdgcn_readlane(__float_as_int(v), l));
}

#define TPB_E 256
#define EDGE_WPB 4
__global__ __launch_bounds__(TPB_E, 3) void edge_kernel(
    const float* __restrict__ x, const float* __restrict__ pos,
    const unsigned int* __restrict__ off, const unsigned int* __restrict__ cur,
    const unsigned int* __restrict__ list,
    const float* __restrict__ W1, const float* __restrict__ b1,
    const float* __restrict__ W2, const float* __restrict__ b2,
    float* __restrict__ agg, int N, int dstStride)
{
    int lane = threadIdx.x & 63;
    int dst0 = blockIdx.x * EDGE_WPB + (threadIdx.x >> 6);

    float w1c[6];
#pragma unroll
    for (int k = 0; k < 6; ++k) w1c[k] = W1[k * 64 + lane];
    float b1c = b1[lane], b2c = b2[lane];
    float w2c[64];
#pragma unroll
    for (int j = 0; j < 64; ++j) w2c[j] = W2[j * 64 + lane];
#pragma unroll
    for (int k = 0; k < 6; ++k) asm volatile("" : "+v"(w1c[k]));
#pragma unroll
    for (int j = 0; j < 64; ++j) asm volatile("" : "+v"(w2c[j]));

    for (int dst = dst0; dst < N; dst += dstStride) {
        unsigned int o0 = off[dst];
        int cnt = (int)(cur[dst] - o0);
        float pi0 = pos[dst * 3 + 0], pi1 = pos[dst * 3 + 1], pi2 = pos[dst * 3 + 2];
        float m = -INFINITY;

        float in0 = 0.f, in1 = 0.f, in2 = 0.f, in3 = 0.f, in4 = 0.f, in5 = 0.f;
        if (lane < 8) {
            int i = lane;
            int s = (i < cnt) ? (int)list[o0 + i] : dst;
            in0 = x[s * 3 + 0]; in1 = x[s * 3 + 1]; in2 = x[s * 3 + 2];
            in3 = pos[s * 3 + 0] - pi0; in4 = pos[s * 3 + 1] - pi1; in5 = pos[s * 3 + 2] - pi2;
        }

        for (int base = 0; base < cnt; base += 8) {
            int nb = min(8, cnt - base);
            float n0 = 0.f, n1 = 0.f, n2 = 0.f, n3 = 0.f, n4 = 0.f, n5 = 0.f;
            if (lane < 8 && base + 8 < cnt) {
                int i = base + 8 + lane;
                int s = (i < cnt) ? (int)list[o0 + i] : dst;
                n0 = x[s * 3 + 0]; n1 = x[s * 3 + 1]; n2 = x[s * 3 + 2];
                n3 = pos[s * 3 + 0] - pi0; n4 = pos[s * 3 + 1] - pi1; n5 = pos[s * 3 + 2] - pi2;
            }
            float h[8];
#pragma unroll
            for (int e = 0; e < 8; ++e) {
                float t = b1c;
                t = fmaf(rl(in0, e), w1c[0], t);
                t = fmaf(rl(in1, e), w1c[1], t);
                t = fmaf(rl(in2, e), w1c[2], t);
                t = fmaf(rl(in3, e), w1c[3], t);
                t = fmaf(rl(in4, e), w1c[4], t);
                t = fmaf(rl(in5, e), w1c[5], t);
                h[e] = fmaxf(t, 0.f);
            }
#pragma unroll
            for (int e = 0; e < 8; ++e) {
                if (e >= nb) break;
                int hh = __float_as_int(h[e]);
                float t0 = b2c, t1 = 0.f, t2 = 0.f, t3 = 0.f;
#pragma unroll
                for (int j = 0; j < 64; j += 4) {
                    t0 = fmaf(__int_as_float(__builtin_amdgcn_readlane(hh, j + 0)), w2c[j + 0], t0);
                    t1 = fmaf(__int_as_float(__builtin_amdgcn_readlane(hh, j + 1)), w2c[j + 1], t1);
                    t2 = fmaf(__int_as_float(__builtin_amdgcn_readlane(hh, j + 2)), w2c[j + 2], t2);
                    t3 = fmaf(__int_as_float(__builtin_amdgcn_readlane(hh, j + 3)), w2c[j + 3], t3);
                }
                m = fmaxf(m, (t0 + t1) + (t2 + t3));
            }
            in0 = n0; in1 = n1; in2 = n2; in3 = n3; in4 = n4; in5 = n5;
        }
        agg[(size_t)dst * 64 + lane] = m;
    }
}

// ===================== node kernel: bf16 MFMA GEMM chain, 64 nodes/block =====================
// Layouts (m89/m120-verified, 16x16x32 bf16):
//   A-frag: lane holds A[m=lane&15][k=quad*8+j]   (one b128 from row-major [m][k])
//   B-frag: lane holds B[k=quad*8+j][n=lane&15]   (one b128 from transposed Wt[n][k])
//   C/D:    reg r = D[row=quad*4+r][col=lane&15]
// Each wave owns 16 node-rows end-to-end -> G1s/G2s/G3f LDS rows are wave-private
// (no barriers in the MFMA chain; 2 barriers before the f32 fc/softmax tail).
#define NNODE 64
__global__ __launch_bounds__(256, 2) void node_kernel(
    const float* __restrict__ agg,
    const unsigned short* __restrict__ W3bt, const float* __restrict__ b3,
    const unsigned short* __restrict__ W4bt, const float* __restrict__ b4,
    const unsigned short* __restrict__ W5bt, const float* __restrict__ b5,
    const float* __restrict__ Wf, const float* __restrict__ bf,
    float* __restrict__ out, int N)
{
    // region0: G1s bf16 [64][136] (17408 B)  -> G3f f32 [64][68] (17408 B, same row stride 272B)
    // region1: G2s bf16 [64][72]  (9216 B)   -> os  f32 [64][41] (10496 B)
    __shared__ __align__(16) char smem[17408 + 10496];
    short* G1s = (short*)smem;
    float* G3f = (float*)smem;
    short* G2s = (short*)(smem + 17408);
    float* os  = (float*)(smem + 17408);

    int tid = threadIdx.x;
    int lane = tid & 63;
    int wm = tid >> 6;            // wave id -> owns node rows [wm*16, wm*16+16)
    int lm = lane & 15;
    int quad = lane >> 4;
    int n0 = blockIdx.x * NNODE;

    // ---- L3: g1[64x128] = relu(agg @ W3 + b3), K=64 ----
    {
        int arow = min(n0 + wm * 16 + lm, N - 1);
        bf16x8 A3[2];
#pragma unroll
        for (int f = 0; f < 2; ++f) {
            const float* p = agg + (size_t)arow * 64 + f * 32 + quad * 8;
            float4 u = *(const float4*)p;
            float4 v = *(const float4*)(p + 4);
            bf16x8 t;
            t[0] = (short)f2bf(u.x); t[1] = (short)f2bf(u.y);
            t[2] = (short)f2bf(u.z); t[3] = (short)f2bf(u.w);
            t[4] = (short)f2bf(v.x); t[5] = (short)f2bf(v.y);
            t[6] = (short)f2bf(v.z); t[7] = (short)f2bf(v.w);
            A3[f] = t;
        }
#pragma unroll
        for (int nt = 0; nt < 8; ++nt) {
            const unsigned short* wb = W3bt + (nt * 16 + lm) * 64 + quad * 8;
            bf16x8 b0 = *(const bf16x8*)wb;
            bf16x8 b1v = *(const bf16x8*)(wb + 32);
            f32x4 c = {0.f, 0.f, 0.f, 0.f};
            c = mfma16(A3[0], b0, c);
            c = mfma16(A3[1], b1v, c);
            float bias = b3[nt * 16 + lm];
#pragma unroll
            for (int r = 0; r < 4; ++r) {
                float v = fmaxf(c[r] + bias, 0.f);
                G1s[(wm * 16 + quad * 4 + r) * 136 + nt * 16 + lm] = (short)f2bf(v);
            }
        }
    }

    // ---- load A-frags for L4 (own rows, K=128 -> 4 frags), reused for all 16 chunks ----
    bf16x8 A4[4];
#pragma unroll
    for (int f = 0; f < 4; ++f)
        A4[f] = *(const bf16x8*)&G1s[(wm * 16 + lm) * 136 + f * 32 + quad * 8];

    // ---- g3 accumulators (4 n-tiles x 4 rows), init with b5 ----
    f32x4 acc3[4];
#pragma unroll
    for (int nt = 0; nt < 4; ++nt) {
        float b = b5[nt * 16 + lm];
        acc3[nt][0] = b; acc3[nt][1] = b; acc3[nt][2] = b; acc3[nt][3] = b;
    }

    // ---- L4+L5 fused over 16 chunks of 64 g2-channels ----
    for (int ch = 0; ch < 16; ++ch) {
        // L4: g2 chunk = relu(g1 @ W4[:, ch*64 .. +64) + b4)
#pragma unroll
        for (int nt = 0; nt < 4; ++nt) {
            const unsigned short* wb = W4bt + (size_t)(ch * 64 + nt * 16 + lm) * 128 + quad * 8;
            f32x4 c = {0.f, 0.f, 0.f, 0.f};
            c = mfma16(A4[0], *(const bf16x8*)wb, c);
            c = mfma16(A4[1], *(const bf16x8*)(wb + 32), c);
            c = mfma16(A4[2], *(const bf16x8*)(wb + 64), c);
            c = mfma16(A4[3], *(const bf16x8*)(wb + 96), c);
            float bias = b4[ch * 64 + nt * 16 + lm];
#pragma unroll
            for (int r = 0; r < 4; ++r) {
                float v = fmaxf(c[r] + bias, 0.f);
                G2s[(wm * 16 + quad * 4 + r) * 72 + nt * 16 + lm] = (short)f2bf(v);
            }
        }
        // L5: g3 += g2chunk @ W5[ch*64 .. +64, :]  (C->A via LDS round-trip, wave-private)
        bf16x8 A5_0 = *(const bf16x8*)&G2s[(wm * 16 + lm) * 72 + quad * 8];
        bf16x8 A5_1 = *(const bf16x8*)&G2s[(wm * 16 + lm) * 72 + 32 + quad * 8];
#pragma unroll
        for (int nt = 0; nt < 4; ++nt) {
            const unsigned short* wb = W5bt + (size_t)(nt * 16 + lm) * 1024 + ch * 64 + quad * 8;
            acc3[nt] = mfma16(A5_0, *(const bf16x8*)wb, acc3[nt]);
            acc3[nt] = mfma16(A5_1, *(const bf16x8*)(wb + 32), acc3[nt]);
        }
    }

    // ---- stage relu(g3) f32 (overlays G1s; same wave-private rows, all G1s reads done) ----
#pragma unroll
    for (int nt = 0; nt < 4; ++nt)
#pragma unroll
        for (int r = 0; r < 4; ++r)
            G3f[(wm * 16 + quad * 4 + r) * 68 + nt * 16 + lm] = fmaxf(acc3[nt][r], 0.f);
    __syncthreads();

    // ---- fc: 64 nodes x 40 outputs (f32 VALU) ----
    for (int idx = tid; idx < NNODE * 40; idx += 256) {
        int ln = idx / 40;
        int c = idx - ln * 40;
        float o = bf[c];
#pragma unroll 4
        for (int j = 0; j < 64; ++j)
            o = fmaf(G3f[ln * 68 + j], Wf[j * 40 + c], o);
        os[ln * 41 + c] = o;
    }
    __syncthreads();

    // ---- log_softmax + store ----
    if (tid < NNODE && n0 + tid < N) {
        int ln = tid;
        float mx = os[ln * 41 + 0];
#pragma unroll
        for (int c = 1; c < 40; ++c) mx = fmaxf(mx, os[ln * 41 + c]);
        float s = 0.f;
#pragma unroll
        for (int c = 0; c < 40; ++c) s += expf(os[ln * 41 + c] - mx);
        float ls = logf(s) + mx;
        float* op = out + (size_t)(n0 + ln) * 40;
#pragma unroll
        for (int c = 0; c < 40; ++c) op[c] = os[ln * 41 + c] - ls;
    }
}

// ============================ launch ============================
extern "C" void kernel_launch(void* const* d_in, const int* in_sizes, int n_in,
                              void* d_out, int out_size, void* d_ws, size_t ws_size,
                              hipStream_t stream) {
    const float* x   = (const float*)d_in[0];
    const float* pos = (const float*)d_in[1];
    const int*   ei  = (const int*)d_in[2];
    const float* W1  = (const float*)d_in[3];
    const float* b1  = (const float*)d_in[4];
    const float* W2  = (const float*)d_in[5];
    const float* b2  = (const float*)d_in[6];
    const float* W3  = (const float*)d_in[7];
    const float* b3  = (const float*)d_in[8];
    const float* W4  = (const float*)d_in[9];
    const float* b4  = (const float*)d_in[10];
    const float* W5  = (const float*)d_in[11];
    const float* b5  = (const float*)d_in[12];
    const float* Wf  = (const float*)d_in[13];
    const float* bf  = (const float*)d_in[14];
    float* out = (float*)d_out;

    int Nn = in_sizes[0] / 3;   // 50000
    int E  = in_sizes[2] / 2;   // 1600000

    char* w = (char*)d_ws;
    size_t p = 0;
    auto take = [&](size_t bytes) { size_t q = p; p = (p + bytes + 255) & ~size_t(255); return (void*)(w + q); };
    unsigned int*   off  = (unsigned int*)take((size_t)Nn * 4);
    unsigned int*   cnt  = (unsigned int*)take((size_t)Nn * 4);   // reused as cursor
    unsigned int*   list = (unsigned int*)take((size_t)(E + Nn) * 4);
    float*          agg  = (float*)take((size_t)Nn * 64 * 4);
    unsigned short* W3bt = (unsigned short*)take(8192 * 2);
    unsigned short* W4bt = (unsigned short*)take(131072 * 2);
    unsigned short* W5bt = (unsigned short*)take(65536 * 2);

    k_convert<<<800, 256, 0, stream>>>(W3, W4, W5, W3bt, W4bt, W5bt);

    k_init_cnt<<<(Nn + 255) / 256, 256, 0, stream>>>(cnt, Nn);
    k_count<<<(E + 255) / 256, 256, 0, stream>>>(ei, E, cnt);
    k_scan<<<1, 1024, 0, stream>>>(cnt, off, Nn);
    k_fill<<<(Nn + 255) / 256, 256, 0, stream>>>(off, cnt, list, Nn);
    k_scatter<<<(E + 255) / 256, 256, 0, stream>>>(ei, E, cnt, list);

    int totalWaves = (Nn + 3) / 4;
    int eBlocks = (totalWaves + EDGE_WPB - 1) / EDGE_WPB;
    int dstStride = eBlocks * EDGE_WPB;
    edge_kernel<<<eBlocks, TPB_E, 0, stream>>>(
        x, pos, off, cnt, list, W1, b1, W2, b2, agg, Nn, dstStride);

    node_kernel<<<(Nn + NNODE - 1) / NNODE, 256, 0, stream>>>(
        agg, W3bt, b3, W4bt, b4, W5bt, b5, Wf, bf, out, Nn);
}

// Round 9
// 642.085 us; speedup vs baseline: 2.1587x; 1.5022x over previous
//
#include <hip/hip_runtime.h>
#include <cstddef>
#include <cmath>

typedef __attribute__((ext_vector_type(8))) short bf16x8;
typedef __attribute__((ext_vector_type(4))) float f32x4;

static __device__ __forceinline__ f32x4 mfma16(bf16x8 a, bf16x8 b, f32x4 c) {
    return __builtin_amdgcn_mfma_f32_16x16x32_bf16(a, b, c, 0, 0, 0);
}
static __device__ __forceinline__ unsigned short f2bf(float f) {
    unsigned int u = __float_as_uint(f);
    return (unsigned short)((u + 0x7FFFu + ((u >> 16) & 1u)) >> 16);
}

// ============================ CSR build ============================
__global__ void k_init_cnt(unsigned int* __restrict__ cnt, int N) {
    int i = blockIdx.x * 256 + threadIdx.x;
    if (i < N) cnt[i] = 1u;   // self-loop pre-counted
}

__global__ void k_count(const int* __restrict__ ei, int E, unsigned int* __restrict__ cnt) {
    int e = blockIdx.x * 256 + threadIdx.x;
    if (e < E) atomicAdd(&cnt[ei[E + e]], 1u);
}

__global__ __launch_bounds__(1024) void k_scan(const unsigned int* __restrict__ cnt,
                                               unsigned int* __restrict__ off, int N) {
    __shared__ unsigned int sums[1024];
    int t = threadIdx.x;
    int chunk = (N + 1023) >> 10;
    int lo = t * chunk, hi = min(lo + chunk, N);
    unsigned int s = 0;
    for (int i = lo; i < hi; ++i) s += cnt[i];
    sums[t] = s;
    __syncthreads();
    for (int d = 1; d < 1024; d <<= 1) {
        unsigned int v = (t >= d) ? sums[t - d] : 0u;
        __syncthreads();
        sums[t] += v;
        __syncthreads();
    }
    unsigned int run = (t == 0) ? 0u : sums[t - 1];
    for (int i = lo; i < hi; ++i) { off[i] = run; run += cnt[i]; }
}

__global__ void k_fill(const unsigned int* __restrict__ off, unsigned int* __restrict__ cur,
                       unsigned int* __restrict__ list, int N) {
    int n = blockIdx.x * 256 + threadIdx.x;
    if (n < N) { unsigned int o = off[n]; list[o] = (unsigned int)n; cur[n] = o + 1u; }
}

__global__ void k_scatter(const int* __restrict__ ei, int E,
                          unsigned int* __restrict__ cur, unsigned int* __restrict__ list) {
    int e = blockIdx.x * 256 + threadIdx.x;
    if (e < E) {
        int d = ei[E + e];
        unsigned int p = atomicAdd(&cur[d], 1u);
        list[p] = (unsigned int)ei[e];
    }
}

// ====== weight converter: f32 [K][N] -> bf16 transposed [N][K] (W1 K-padded to 32) ======
__global__ void k_convert(const float* __restrict__ W1, const float* __restrict__ W2,
                          const float* __restrict__ W3, const float* __restrict__ W4,
                          const float* __restrict__ W5,
                          unsigned short* __restrict__ W1bt, unsigned short* __restrict__ W2bt,
                          unsigned short* __restrict__ W3bt, unsigned short* __restrict__ W4bt,
                          unsigned short* __restrict__ W5bt) {
    int id = blockIdx.x * 256 + threadIdx.x;
    if (id < 2048) {                               // W1: [6][64] -> [64][32] zero-padded
        int n = id >> 5, k = id & 31;
        W1bt[id] = (k < 6) ? f2bf(W1[k * 64 + n]) : (unsigned short)0;
    } else if (id < 2048 + 4096) {                 // W2: [64][64] -> [64][64]
        int t = id - 2048;
        int n = t >> 6, k = t & 63;
        W2bt[t] = f2bf(W2[k * 64 + n]);
    } else if (id < 6144 + 8192) {                 // W3: [64][128] -> [128][64]
        int t = id - 6144;
        int n = t >> 6, k = t & 63;
        W3bt[t] = f2bf(W3[k * 128 + n]);
    } else if (id < 14336 + 131072) {              // W4: [128][1024] -> [1024][128]
        int t = id - 14336;
        int n = t >> 7, k = t & 127;
        W4bt[t] = f2bf(W4[k * 1024 + n]);
    } else if (id < 145408 + 65536) {              // W5: [1024][64] -> [64][1024]
        int t = id - 145408;
        int n = t >> 10, k = t & 1023;
        W5bt[t] = f2bf(W5[k * 64 + n]);
    }
}

// ===================== edge kernel: MFMA, one wave per dst, 16 msgs/tile =====================
// A-frag: lane holds A[m=lane&15][k=quad*8+j]; B-frag: B[k=quad*8+j][n=lane&15];
// C/D: reg r = D[row=quad*4+r][col=lane&15]  (m89/m120-verified layouts).
// Tile padding duplicates the last message of the dst (max is idempotent -> no masking).
// h C->A round-trip goes through a wave-private LDS patch (no barriers).
#define TPB_E 256
#define EDGE_WPB 4
__global__ __launch_bounds__(TPB_E, 3) void edge_kernel(
    const float* __restrict__ x, const float* __restrict__ pos,
    const unsigned int* __restrict__ off, const unsigned int* __restrict__ cur,
    const unsigned int* __restrict__ list,
    const unsigned short* __restrict__ W1bt, const float* __restrict__ b1,
    const unsigned short* __restrict__ W2bt, const float* __restrict__ b2,
    float* __restrict__ agg, int N, int dstStride)
{
    __shared__ __align__(16) short Hs[4][16 * 72];   // per-wave h patch (stride 72: 16B-aligned rows)

    int tid = threadIdx.x;
    int lane = tid & 63;
    int w = tid >> 6;
    int lm = lane & 15;
    int quad = lane >> 4;
    short* H = Hs[w];
    int dst0 = blockIdx.x * EDGE_WPB + w;

    // preload B-frags + biases (once per wave)
    bf16x8 B1f[4], B2f[4][2];
    float b1c[4], b2c[4];
#pragma unroll
    for (int nt = 0; nt < 4; ++nt) {
        B1f[nt] = *(const bf16x8*)&W1bt[(nt * 16 + lm) * 32 + quad * 8];
        B2f[nt][0] = *(const bf16x8*)&W2bt[(nt * 16 + lm) * 64 + quad * 8];
        B2f[nt][1] = *(const bf16x8*)&W2bt[(nt * 16 + lm) * 64 + 32 + quad * 8];
        b1c[nt] = b1[nt * 16 + lm];
        b2c[nt] = b2[nt * 16 + lm];
    }

    for (int dst = dst0; dst < N; dst += dstStride) {
        unsigned int o0 = off[dst];
        int cnt = (int)(cur[dst] - o0);
        float pi0 = pos[dst * 3 + 0], pi1 = pos[dst * 3 + 1], pi2 = pos[dst * 3 + 2];

        float m0 = -INFINITY, m1 = -INFINITY, m2 = -INFINITY, m3 = -INFINITY;

        for (int base = 0; base < cnt; base += 16) {
            // ---- stage A-frag: quad0 lanes gather msg lm's 6 features; other quads zero ----
            bf16x8 A = {0, 0, 0, 0, 0, 0, 0, 0};
            if (quad == 0) {
                int i = min(base + lm, cnt - 1);         // pad = duplicate last (idempotent max)
                int s = (int)list[o0 + i];
                float f0 = x[s * 3 + 0], f1 = x[s * 3 + 1], f2 = x[s * 3 + 2];
                float f3 = pos[s * 3 + 0] - pi0;
                float f4 = pos[s * 3 + 1] - pi1;
                float f5 = pos[s * 3 + 2] - pi2;
                A[0] = (short)f2bf(f0); A[1] = (short)f2bf(f1); A[2] = (short)f2bf(f2);
                A[3] = (short)f2bf(f3); A[4] = (short)f2bf(f4); A[5] = (short)f2bf(f5);
            }

            // ---- L1: h[16][64] = relu(A @ W1 + b1) ----
#pragma unroll
            for (int nt = 0; nt < 4; ++nt) {
                f32x4 c = {0.f, 0.f, 0.f, 0.f};
                c = mfma16(A, B1f[nt], c);
#pragma unroll
                for (int r = 0; r < 4; ++r) {
                    float v = fmaxf(c[r] + b1c[nt], 0.f);
                    H[(quad * 4 + r) * 72 + nt * 16 + lm] = (short)f2bf(v);
                }
            }
            // wave-private LDS; compiler inserts lgkmcnt before the dependent reads
            bf16x8 A2a = *(const bf16x8*)&H[lm * 72 + quad * 8];
            bf16x8 A2b = *(const bf16x8*)&H[lm * 72 + 32 + quad * 8];

            // ---- L2 + per-lane row max (rows quad*4..+3), running max across tiles ----
            {
                f32x4 c = {0.f, 0.f, 0.f, 0.f};
                c = mfma16(A2a, B2f[0][0], c); c = mfma16(A2b, B2f[0][1], c);
                m0 = fmaxf(m0, fmaxf(fmaxf(c[0], c[1]), fmaxf(c[2], c[3])));
            }
            {
                f32x4 c = {0.f, 0.f, 0.f, 0.f};
                c = mfma16(A2a, B2f[1][0], c); c = mfma16(A2b, B2f[1][1], c);
                m1 = fmaxf(m1, fmaxf(fmaxf(c[0], c[1]), fmaxf(c[2], c[3])));
            }
            {
                f32x4 c = {0.f, 0.f, 0.f, 0.f};
                c = mfma16(A2a, B2f[2][0], c); c = mfma16(A2b, B2f[2][1], c);
                m2 = fmaxf(m2, fmaxf(fmaxf(c[0], c[1]), fmaxf(c[2], c[3])));
            }
            {
                f32x4 c = {0.f, 0.f, 0.f, 0.f};
                c = mfma16(A2a, B2f[3][0], c); c = mfma16(A2b, B2f[3][1], c);
                m3 = fmaxf(m3, fmaxf(fmaxf(c[0], c[1]), fmaxf(c[2], c[3])));
            }
        }

        // ---- cross-quad butterfly: max over all 16 rows ----
        m0 = fmaxf(m0, __shfl_xor(m0, 16, 64)); m0 = fmaxf(m0, __shfl_xor(m0, 32, 64));
        m1 = fmaxf(m1, __shfl_xor(m1, 16, 64)); m1 = fmaxf(m1, __shfl_xor(m1, 32, 64));
        m2 = fmaxf(m2, __shfl_xor(m2, 16, 64)); m2 = fmaxf(m2, __shfl_xor(m2, 32, 64));
        m3 = fmaxf(m3, __shfl_xor(m3, 16, 64)); m3 = fmaxf(m3, __shfl_xor(m3, 32, 64));

        // bias added post-max (uniform per column); lane=quad*16+lm stores channel quad*16+lm
        float mv = (quad == 0) ? m0 : (quad == 1) ? m1 : (quad == 2) ? m2 : m3;
        agg[(size_t)dst * 64 + lane] = mv + b2c[quad];
    }
}

// ===================== node kernel: bf16 MFMA GEMM chain, 64 nodes/block (unchanged R8) =====================
#define NNODE 64
__global__ __launch_bounds__(256, 2) void node_kernel(
    const float* __restrict__ agg,
    const unsigned short* __restrict__ W3bt, const float* __restrict__ b3,
    const unsigned short* __restrict__ W4bt, const float* __restrict__ b4,
    const unsigned short* __restrict__ W5bt, const float* __restrict__ b5,
    const float* __restrict__ Wf, const float* __restrict__ bf,
    float* __restrict__ out, int N)
{
    __shared__ __align__(16) char smem[17408 + 10496];
    short* G1s = (short*)smem;
    float* G3f = (float*)smem;
    short* G2s = (short*)(smem + 17408);
    float* os  = (float*)(smem + 17408);

    int tid = threadIdx.x;
    int lane = tid & 63;
    int wm = tid >> 6;
    int lm = lane & 15;
    int quad = lane >> 4;
    int n0 = blockIdx.x * NNODE;

    // ---- L3: g1[64x128] = relu(agg @ W3 + b3), K=64 ----
    {
        int arow = min(n0 + wm * 16 + lm, N - 1);
        bf16x8 A3[2];
#pragma unroll
        for (int f = 0; f < 2; ++f) {
            const float* p = agg + (size_t)arow * 64 + f * 32 + quad * 8;
            float4 u = *(const float4*)p;
            float4 v = *(const float4*)(p + 4);
            bf16x8 t;
            t[0] = (short)f2bf(u.x); t[1] = (short)f2bf(u.y);
            t[2] = (short)f2bf(u.z); t[3] = (short)f2bf(u.w);
            t[4] = (short)f2bf(v.x); t[5] = (short)f2bf(v.y);
            t[6] = (short)f2bf(v.z); t[7] = (short)f2bf(v.w);
            A3[f] = t;
        }
#pragma unroll
        for (int nt = 0; nt < 8; ++nt) {
            const unsigned short* wb = W3bt + (nt * 16 + lm) * 64 + quad * 8;
            bf16x8 b0 = *(const bf16x8*)wb;
            bf16x8 b1v = *(const bf16x8*)(wb + 32);
            f32x4 c = {0.f, 0.f, 0.f, 0.f};
            c = mfma16(A3[0], b0, c);
            c = mfma16(A3[1], b1v, c);
            float bias = b3[nt * 16 + lm];
#pragma unroll
            for (int r = 0; r < 4; ++r) {
                float v = fmaxf(c[r] + bias, 0.f);
                G1s[(wm * 16 + quad * 4 + r) * 136 + nt * 16 + lm] = (short)f2bf(v);
            }
        }
    }

    bf16x8 A4[4];
#pragma unroll
    for (int f = 0; f < 4; ++f)
        A4[f] = *(const bf16x8*)&G1s[(wm * 16 + lm) * 136 + f * 32 + quad * 8];

    f32x4 acc3[4];
#pragma unroll
    for (int nt = 0; nt < 4; ++nt) {
        float b = b5[nt * 16 + lm];
        acc3[nt][0] = b; acc3[nt][1] = b; acc3[nt][2] = b; acc3[nt][3] = b;
    }

    for (int ch = 0; ch < 16; ++ch) {
#pragma unroll
        for (int nt = 0; nt < 4; ++nt) {
            const unsigned short* wb = W4bt + (size_t)(ch * 64 + nt * 16 + lm) * 128 + quad * 8;
            f32x4 c = {0.f, 0.f, 0.f, 0.f};
            c = mfma16(A4[0], *(const bf16x8*)wb, c);
            c = mfma16(A4[1], *(const bf16x8*)(wb + 32), c);
            c = mfma16(A4[2], *(const bf16x8*)(wb + 64), c);
            c = mfma16(A4[3], *(const bf16x8*)(wb + 96), c);
            float bias = b4[ch * 64 + nt * 16 + lm];
#pragma unroll
            for (int r = 0; r < 4; ++r) {
                float v = fmaxf(c[r] + bias, 0.f);
                G2s[(wm * 16 + quad * 4 + r) * 72 + nt * 16 + lm] = (short)f2bf(v);
            }
        }
        bf16x8 A5_0 = *(const bf16x8*)&G2s[(wm * 16 + lm) * 72 + quad * 8];
        bf16x8 A5_1 = *(const bf16x8*)&G2s[(wm * 16 + lm) * 72 + 32 + quad * 8];
#pragma unroll
        for (int nt = 0; nt < 4; ++nt) {
            const unsigned short* wb = W5bt + (size_t)(nt * 16 + lm) * 1024 + ch * 64 + quad * 8;
            acc3[nt] = mfma16(A5_0, *(const bf16x8*)wb, acc3[nt]);
            acc3[nt] = mfma16(A5_1, *(const bf16x8*)(wb + 32), acc3[nt]);
        }
    }

#pragma unroll
    for (int nt = 0; nt < 4; ++nt)
#pragma unroll
        for (int r = 0; r < 4; ++r)
            G3f[(wm * 16 + quad * 4 + r) * 68 + nt * 16 + lm] = fmaxf(acc3[nt][r], 0.f);
    __syncthreads();

    for (int idx = tid; idx < NNODE * 40; idx += 256) {
        int ln = idx / 40;
        int c = idx - ln * 40;
        float o = bf[c];
#pragma unroll 4
        for (int j = 0; j < 64; ++j)
            o = fmaf(G3f[ln * 68 + j], Wf[j * 40 + c], o);
        os[ln * 41 + c] = o;
    }
    __syncthreads();

    if (tid < NNODE && n0 + tid < N) {
        int ln = tid;
        float mx = os[ln * 41 + 0];
#pragma unroll
        for (int c = 1; c < 40; ++c) mx = fmaxf(mx, os[ln * 41 + c]);
        float s = 0.f;
#pragma unroll
        for (int c = 0; c < 40; ++c) s += expf(os[ln * 41 + c] - mx);
        float ls = logf(s) + mx;
        float* op = out + (size_t)(n0 + ln) * 40;
#pragma unroll
        for (int c = 0; c < 40; ++c) op[c] = os[ln * 41 + c] - ls;
    }
}

// ============================ launch ============================
extern "C" void kernel_launch(void* const* d_in, const int* in_sizes, int n_in,
                              void* d_out, int out_size, void* d_ws, size_t ws_size,
                              hipStream_t stream) {
    const float* x   = (const float*)d_in[0];
    const float* pos = (const float*)d_in[1];
    const int*   ei  = (const int*)d_in[2];
    const float* W1  = (const float*)d_in[3];
    const float* b1  = (const float*)d_in[4];
    const float* W2  = (const float*)d_in[5];
    const float* b2  = (const float*)d_in[6];
    const float* W3  = (const float*)d_in[7];
    const float* b3  = (const float*)d_in[8];
    const float* W4  = (const float*)d_in[9];
    const float* b4  = (const float*)d_in[10];
    const float* W5  = (const float*)d_in[11];
    const float* b5  = (const float*)d_in[12];
    const float* Wf  = (const float*)d_in[13];
    const float* bf  = (const float*)d_in[14];
    float* out = (float*)d_out;

    int Nn = in_sizes[0] / 3;   // 50000
    int E  = in_sizes[2] / 2;   // 1600000

    char* w = (char*)d_ws;
    size_t p = 0;
    auto take = [&](size_t bytes) { size_t q = p; p = (p + bytes + 255) & ~size_t(255); return (void*)(w + q); };
    unsigned int*   off  = (unsigned int*)take((size_t)Nn * 4);
    unsigned int*   cnt  = (unsigned int*)take((size_t)Nn * 4);   // reused as cursor
    unsigned int*   list = (unsigned int*)take((size_t)(E + Nn) * 4);
    float*          agg  = (float*)take((size_t)Nn * 64 * 4);
    unsigned short* W1bt = (unsigned short*)take(2048 * 2);
    unsigned short* W2bt = (unsigned short*)take(4096 * 2);
    unsigned short* W3bt = (unsigned short*)take(8192 * 2);
    unsigned short* W4bt = (unsigned short*)take(131072 * 2);
    unsigned short* W5bt = (unsigned short*)take(65536 * 2);

    k_convert<<<(2048 + 4096 + 8192 + 131072 + 65536 + 255) / 256, 256, 0, stream>>>(
        W1, W2, W3, W4, W5, W1bt, W2bt, W3bt, W4bt, W5bt);

    k_init_cnt<<<(Nn + 255) / 256, 256, 0, stream>>>(cnt, Nn);
    k_count<<<(E + 255) / 256, 256, 0, stream>>>(ei, E, cnt);
    k_scan<<<1, 1024, 0, stream>>>(cnt, off, Nn);
    k_fill<<<(Nn + 255) / 256, 256, 0, stream>>>(off, cnt, list, Nn);
    k_scatter<<<(E + 255) / 256, 256, 0, stream>>>(ei, E, cnt, list);

    int totalWaves = (Nn + 3) / 4;
    int eBlocks = (totalWaves + EDGE_WPB - 1) / EDGE_WPB;
    int dstStride = eBlocks * EDGE_WPB;
    edge_kernel<<<eBlocks, TPB_E, 0, stream>>>(
        x, pos, off, cnt, list, W1bt, b1, W2bt, b2, agg, Nn, dstStride);

    node_kernel<<<(Nn + NNODE - 1) / NNODE, 256, 0, stream>>>(
        agg, W3bt, b3, W4bt, b4, W5bt, b5, Wf, bf, out, Nn);
}